// Round 4
// baseline (163.270 us; speedup 1.0000x reference)
//
#include <hip/hip_runtime.h>

#define Hd 512
#define N2d 16
#define Rd 32
#define Ld 4096
#define NCHUNK 256
#define CLEN (Ld / NCHUNK)        // 16
#define NCH (Hd * N2d)            // 8192 chains
#define NGRP 8                    // chunks per prefix group (lookback <= 7)
#define NGROUPS (NCHUNK / NGRP)   // 32

// ---------------------------------------------------------------------------
// Per-thread constant setup: 4 consecutive n of one h. fast == true when Are
// uniform and Aim arithmetic across the 4 (true for S4D init A = -1 + i*n).
// ---------------------------------------------------------------------------
__device__ __forceinline__ bool load_consts4(const float* A_log, const float* A_im,
        const float* B_param, int hnb,
        float* Are, float* Aim, float* BAr, float* BAi) {
    #pragma unroll
    for (int j = 0; j < 4; ++j) {
        int hn = hnb + j;
        Are[j] = -__expf(A_log[hn]);
        Aim[j] = A_im[hn];
        float Bre = B_param[2 * hn];
        float Bim = B_param[2 * hn + 1];
        float inv = __builtin_amdgcn_rcpf(Are[j] * Are[j] + Aim[j] * Aim[j]);
        BAr[j] = (Bre * Are[j] + Bim * Aim[j]) * inv;   // Bc*conj(A)/|A|^2
        BAi[j] = (Bim * Are[j] - Bre * Aim[j]) * inv;
    }
    float d1 = Aim[1] - Aim[0], d2 = Aim[2] - Aim[1], d3 = Aim[3] - Aim[2];
    return (Are[1] == Are[0]) && (Are[2] == Are[0]) && (Are[3] == Are[0]) &&
           (d1 == d2) && (d2 == d3);
}

// ---------------------------------------------------------------------------
// Kernel 1: dt = softplus(u@xprojT@dtwT + b); writes du[l][h] = (dt, u/dt).
// dt_w read directly as per-lane contiguous float4 (no transpose pass).
// ---------------------------------------------------------------------------
__global__ __launch_bounds__(256) void k_dt(const float* __restrict__ u,
                                            const float* __restrict__ xproj_w,
                                            const float* __restrict__ dt_w,
                                            const float* __restrict__ dt_b,
                                            float2* __restrict__ du_out) {
    __shared__ float u_s[8][Hd];
    __shared__ float dtu_s[8][Rd];
    const int t = threadIdx.x;
    const int l0 = blockIdx.x * 8;

    #pragma unroll
    for (int i = 0; i < 16; ++i) {
        int idx = t + i * 256;
        ((float*)u_s)[idx] = u[l0 * Hd + idx];
    }
    __syncthreads();

    const int r = t >> 3;
    const int j = t & 7;
    float part[8];
    #pragma unroll
    for (int l = 0; l < 8; ++l) part[l] = 0.f;
    for (int k = 0; k < 64; ++k) {
        float w = xproj_w[r * Hd + k * 8 + j];
        #pragma unroll
        for (int l = 0; l < 8; ++l) part[l] = fmaf(u_s[l][k * 8 + j], w, part[l]);
    }
    #pragma unroll
    for (int off = 1; off < 8; off <<= 1) {
        #pragma unroll
        for (int l = 0; l < 8; ++l) part[l] += __shfl_xor(part[l], off);
    }
    if (j == 0) {
        #pragma unroll
        for (int l = 0; l < 8; ++l) dtu_s[l][r] = part[l];
    }
    __syncthreads();

    #pragma unroll
    for (int hb = 0; hb < 2; ++hb) {
        int h = hb * 256 + t;
        float bias = dt_b[h];
        float acc[8];
        #pragma unroll
        for (int l = 0; l < 8; ++l) acc[l] = bias;
        #pragma unroll
        for (int rb = 0; rb < 8; ++rb) {
            float4 w = *(const float4*)&dt_w[h * Rd + rb * 4];
            #pragma unroll
            for (int l = 0; l < 8; ++l) {
                acc[l] = fmaf(dtu_s[l][rb * 4 + 0], w.x, acc[l]);
                acc[l] = fmaf(dtu_s[l][rb * 4 + 1], w.y, acc[l]);
                acc[l] = fmaf(dtu_s[l][rb * 4 + 2], w.z, acc[l]);
                acc[l] = fmaf(dtu_s[l][rb * 4 + 3], w.w, acc[l]);
            }
        }
        #pragma unroll
        for (int l = 0; l < 8; ++l) {
            float x = acc[l];
            float sp = fmaxf(x, 0.f) + log1pf(__expf(-fabsf(x)));  // softplus
            float uv = u_s[l][h];
            float us = uv * __builtin_amdgcn_rcpf(fmaxf(sp, 1e-30f));
            du_out[(l0 + l) * Hd + h] = make_float2(sp, us);
        }
    }
}

// ---------------------------------------------------------------------------
// Kernel 2: per-chunk scan (h0=0) -> PS[c][chain] = (P.re, P.im, S.re, S.im).
// CLEN=16, whole chunk prefetched to registers. Grid (NCHUNK, H/64) = 2048.
// ---------------------------------------------------------------------------
__global__ __launch_bounds__(256) void k_chunk(const float2* __restrict__ du,
        const float* __restrict__ A_log, const float* __restrict__ A_im,
        const float* __restrict__ B_param, float4* __restrict__ PS) {
    const int t = threadIdx.x;
    const int q = t & 3;
    const int hh = blockIdx.y * 64 + (t >> 2);
    const int c = blockIdx.x;
    const int hnb = hh * N2d + q * 4;
    const int lbase = c * CLEN;

    float2 d[CLEN];
    #pragma unroll
    for (int k = 0; k < CLEN; ++k) d[k] = du[(lbase + k) * Hd + hh];

    float Are[4], Aim[4], BAr[4], BAi[4];
    const bool fast = load_consts4(A_log, A_im, B_param, hnb, Are, Aim, BAr, BAi);
    float sr[4] = {0.f, 0.f, 0.f, 0.f}, si[4] = {0.f, 0.f, 0.f, 0.f};
    float sdt = 0.f;
    if (fast) {
        const float Are0 = Are[0], Aim0 = Aim[0], dA = Aim[1] - Aim[0];
        #pragma unroll
        for (int k = 0; k < CLEN; ++k) {
            float dtv = d[k].x, us = d[k].y;
            sdt += dtv;
            float er = __expf(dtv * Are0);
            float s0, c0, sd, cd;
            __sincosf(dtv * Aim0, &s0, &c0);
            __sincosf(dtv * dA, &sd, &cd);
            float ar = er * c0, ai = er * s0;
            #pragma unroll
            for (int jj = 0; jj < 4; ++jj) {
                float gr = fmaf(ar, us, -us);
                float gi = ai * us;
                float nr = fmaf(ar, sr[jj], fmaf(-ai, si[jj], fmaf(gr, BAr[jj], -gi * BAi[jj])));
                float ni = fmaf(ar, si[jj], fmaf( ai, sr[jj], fmaf(gr, BAi[jj],  gi * BAr[jj])));
                sr[jj] = nr; si[jj] = ni;
                if (jj < 3) {
                    float tr = fmaf(ar, cd, -ai * sd);
                    ai = fmaf(ai, cd, ar * sd);
                    ar = tr;
                }
            }
        }
    } else {
        #pragma unroll
        for (int k = 0; k < CLEN; ++k) {
            float dtv = d[k].x, us = d[k].y;
            sdt += dtv;
            #pragma unroll
            for (int jj = 0; jj < 4; ++jj) {
                float er = __expf(dtv * Are[jj]);
                float s, cc;
                __sincosf(dtv * Aim[jj], &s, &cc);
                float ar = er * cc, ai = er * s;
                float gr = fmaf(ar, us, -us);
                float gi = ai * us;
                float nr = fmaf(ar, sr[jj], fmaf(-ai, si[jj], fmaf(gr, BAr[jj], -gi * BAi[jj])));
                float ni = fmaf(ar, si[jj], fmaf( ai, sr[jj], fmaf(gr, BAi[jj],  gi * BAr[jj])));
                sr[jj] = nr; si[jj] = ni;
            }
        }
    }
    int base = c * NCH + hnb;
    #pragma unroll
    for (int jj = 0; jj < 4; ++jj) {
        float er = __expf(sdt * Are[jj]);
        float s, cc;
        __sincosf(sdt * Aim[jj], &s, &cc);
        PS[base + jj] = make_float4(er * cc, er * s, sr[jj], si[jj]);
    }
}

// ---------------------------------------------------------------------------
// Kernel 3a: per-(chain, group) aggregate over NGRP=8 chunks -> Gps.
// 262144 threads; writes only 4 MB (no dead Ilocal/Pcum traffic).
// ---------------------------------------------------------------------------
__global__ __launch_bounds__(256) void k_gagg(const float4* __restrict__ PS,
                                              float4* __restrict__ Gps) {
    int idx = blockIdx.x * 256 + threadIdx.x;   // 0..262143
    int chain = idx & (NCH - 1);
    int g = idx >> 13;                          // 0..31
    float4 ps[NGRP];
    #pragma unroll
    for (int i = 0; i < NGRP; ++i)
        ps[i] = PS[(g * NGRP + i) * NCH + chain];
    float pr = 1.f, pi = 0.f, hr = 0.f, hi = 0.f;
    #pragma unroll
    for (int i = 0; i < NGRP; ++i) {
        float nhr = fmaf(ps[i].x, hr, fmaf(-ps[i].y, hi, ps[i].z));
        float nhi = fmaf(ps[i].x, hi, fmaf( ps[i].y, hr, ps[i].w));
        float npr = fmaf(ps[i].x, pr, -ps[i].y * pi);
        float npi = fmaf(ps[i].x, pi,  ps[i].y * pr);
        hr = nhr; hi = nhi; pr = npr; pi = npi;
    }
    Gps[g * NCH + chain] = make_float4(pr, pi, hr, hi);
}

// ---------------------------------------------------------------------------
// Kernel 3b: scan 32 group aggregates per chain -> group-start state H0g.
// ---------------------------------------------------------------------------
__global__ __launch_bounds__(256) void k_gscan(const float4* __restrict__ Gps,
                                               float2* __restrict__ H0g) {
    int chain = blockIdx.x * 256 + threadIdx.x;  // 0..8191
    float hr = 0.f, hi = 0.f;
    #pragma unroll
    for (int gb = 0; gb < NGROUPS / 8; ++gb) {
        float4 gp[8];
        #pragma unroll
        for (int i = 0; i < 8; ++i)
            gp[i] = Gps[(gb * 8 + i) * NCH + chain];
        #pragma unroll
        for (int i = 0; i < 8; ++i) {
            H0g[(gb * 8 + i) * NCH + chain] = make_float2(hr, hi);
            float nr = fmaf(gp[i].x, hr, fmaf(-gp[i].y, hi, gp[i].z));
            float ni = fmaf(gp[i].x, hi, fmaf( gp[i].y, hr, gp[i].w));
            hr = nr; hi = ni;
        }
    }
}

// ---------------------------------------------------------------------------
// Kernel 4: re-scan chunks with correct init; emit y.
// Init state composed by in-group lookback: start at H0g[group], fold the
// <=7 predecessor chunk aggregates (block-uniform loop, L2/L3-served).
// ---------------------------------------------------------------------------
__global__ __launch_bounds__(256) void k_scan(const float2* __restrict__ du,
        const float* __restrict__ A_log, const float* __restrict__ A_im,
        const float* __restrict__ B_param, const float* __restrict__ C_param,
        const float* __restrict__ Dp, const float4* __restrict__ PS,
        const float2* __restrict__ H0g, float* __restrict__ out) {
    const int t = threadIdx.x;
    const int q = t & 3;
    const int hh = blockIdx.y * 64 + (t >> 2);
    const int c = blockIdx.x;
    const int g = c >> 3;                // NGRP = 8
    const int hnb = hh * N2d + q * 4;
    const int lbase = c * CLEN;

    float2 d[CLEN];
    #pragma unroll
    for (int k = 0; k < CLEN; ++k) d[k] = du[(lbase + k) * Hd + hh];

    float Are[4], Aim[4], BAr[4], BAi[4], Cre[4], Cim[4];
    const bool fast = load_consts4(A_log, A_im, B_param, hnb, Are, Aim, BAr, BAi);
    #pragma unroll
    for (int jj = 0; jj < 4; ++jj) {
        Cre[jj] = C_param[2 * (hnb + jj)];
        Cim[jj] = C_param[2 * (hnb + jj) + 1];
    }
    const float Dv = Dp[hh];

    // ---- init state via lookback ----
    float hr[4], hi[4];
    #pragma unroll
    for (int jj = 0; jj < 4; ++jj) {
        float2 h0 = H0g[g * NCH + hnb + jj];
        hr[jj] = h0.x; hi[jj] = h0.y;
    }
    for (int cp = g * NGRP; cp < c; ++cp) {      // uniform per block (0..7 iters)
        float4 ps[4];
        #pragma unroll
        for (int jj = 0; jj < 4; ++jj) ps[jj] = PS[cp * NCH + hnb + jj];
        #pragma unroll
        for (int jj = 0; jj < 4; ++jj) {
            float nr = fmaf(ps[jj].x, hr[jj], fmaf(-ps[jj].y, hi[jj], ps[jj].z));
            float ni = fmaf(ps[jj].x, hi[jj], fmaf( ps[jj].y, hr[jj], ps[jj].w));
            hr[jj] = nr; hi[jj] = ni;
        }
    }

    if (fast) {
        const float Are0 = Are[0], Aim0 = Aim[0], dA = Aim[1] - Aim[0];
        #pragma unroll
        for (int k = 0; k < CLEN; ++k) {
            int l = lbase + k;
            float dtv = d[k].x, us = d[k].y;
            float er = __expf(dtv * Are0);
            float s0, c0, sd, cd;
            __sincosf(dtv * Aim0, &s0, &c0);
            __sincosf(dtv * dA, &sd, &cd);
            float ar = er * c0, ai = er * s0;
            float yv = 0.f;
            #pragma unroll
            for (int jj = 0; jj < 4; ++jj) {
                float gr = fmaf(ar, us, -us);
                float gi = ai * us;
                float nr = fmaf(ar, hr[jj], fmaf(-ai, hi[jj], fmaf(gr, BAr[jj], -gi * BAi[jj])));
                float ni = fmaf(ar, hi[jj], fmaf( ai, hr[jj], fmaf(gr, BAi[jj],  gi * BAr[jj])));
                hr[jj] = nr; hi[jj] = ni;
                yv = fmaf(nr, Cre[jj], fmaf(-ni, Cim[jj], yv));
                if (jj < 3) {
                    float tr = fmaf(ar, cd, -ai * sd);
                    ai = fmaf(ai, cd, ar * sd);
                    ar = tr;
                }
            }
            yv += __shfl_xor(yv, 1);
            yv += __shfl_xor(yv, 2);
            if (q == 0) out[l * Hd + hh] = fmaf(dtv * us, Dv, yv);
        }
    } else {
        #pragma unroll
        for (int k = 0; k < CLEN; ++k) {
            int l = lbase + k;
            float dtv = d[k].x, us = d[k].y;
            float yv = 0.f;
            #pragma unroll
            for (int jj = 0; jj < 4; ++jj) {
                float er = __expf(dtv * Are[jj]);
                float s, cc;
                __sincosf(dtv * Aim[jj], &s, &cc);
                float ar = er * cc, ai = er * s;
                float gr = fmaf(ar, us, -us);
                float gi = ai * us;
                float nr = fmaf(ar, hr[jj], fmaf(-ai, hi[jj], fmaf(gr, BAr[jj], -gi * BAi[jj])));
                float ni = fmaf(ar, hi[jj], fmaf( ai, hr[jj], fmaf(gr, BAi[jj],  gi * BAr[jj])));
                hr[jj] = nr; hi[jj] = ni;
                yv = fmaf(nr, Cre[jj], fmaf(-ni, Cim[jj], yv));
            }
            yv += __shfl_xor(yv, 1);
            yv += __shfl_xor(yv, 2);
            if (q == 0) out[l * Hd + hh] = fmaf(dtv * us, Dv, yv);
        }
    }
}

extern "C" void kernel_launch(void* const* d_in, const int* in_sizes, int n_in,
                              void* d_out, int out_size, void* d_ws, size_t ws_size,
                              hipStream_t stream) {
    const float* u        = (const float*)d_in[0];
    const float* A_log    = (const float*)d_in[1];
    const float* A_im     = (const float*)d_in[2];
    const float* B_param  = (const float*)d_in[3];
    const float* C_param  = (const float*)d_in[4];
    const float* Dp       = (const float*)d_in[5];
    const float* dt_w     = (const float*)d_in[6];
    const float* dt_b     = (const float*)d_in[7];
    const float* xproj_w  = (const float*)d_in[8];

    // ws layout: du[L*H f2] | PS[NCHUNK*NCH f4] | Gps[NGROUPS*NCH f4] | H0g[.. f2]
    float2* du  = (float2*)d_ws;
    float4* PS  = (float4*)(du + (size_t)Ld * Hd);
    float4* Gps = PS + (size_t)NCHUNK * NCH;
    float2* H0g = (float2*)(Gps + (size_t)NGROUPS * NCH);
    float*  out = (float*)d_out;

    k_dt<<<Ld / 8, 256, 0, stream>>>(u, xproj_w, dt_w, dt_b, du);
    dim3 g2(NCHUNK, Hd / 64);
    k_chunk<<<g2, 256, 0, stream>>>(du, A_log, A_im, B_param, PS);
    k_gagg<<<(NCH * NGROUPS) / 256, 256, 0, stream>>>(PS, Gps);
    k_gscan<<<NCH / 256, 256, 0, stream>>>(Gps, H0g);
    k_scan<<<g2, 256, 0, stream>>>(du, A_log, A_im, B_param, C_param, Dp,
                                   PS, H0g, out);
}

// Round 5
// 148.804 us; speedup vs baseline: 1.0972x; 1.0972x over previous
//
#include <hip/hip_runtime.h>

#define Hd 512
#define N2d 16
#define Rd 32
#define Ld 4096
#define NCHUNK 128
#define CLEN (Ld / NCHUNK)        // 32
#define NCH (Hd * N2d)            // 8192 chains
#define NGRP 16                   // chunks per prefix group
#define NGROUPS (NCHUNK / NGRP)   // 8

// ---------------------------------------------------------------------------
// Per-thread constant setup: 4 consecutive n of one h. fast == true when Are
// uniform and Aim arithmetic across the 4 (true for S4D init A = -1 + i*n).
// ---------------------------------------------------------------------------
__device__ __forceinline__ bool load_consts4(const float* A_log, const float* A_im,
        const float* B_param, int hnb,
        float* Are, float* Aim, float* BAr, float* BAi) {
    #pragma unroll
    for (int j = 0; j < 4; ++j) {
        int hn = hnb + j;
        Are[j] = -__expf(A_log[hn]);
        Aim[j] = A_im[hn];
        float Bre = B_param[2 * hn];
        float Bim = B_param[2 * hn + 1];
        float inv = __builtin_amdgcn_rcpf(Are[j] * Are[j] + Aim[j] * Aim[j]);
        BAr[j] = (Bre * Are[j] + Bim * Aim[j]) * inv;   // Bc*conj(A)/|A|^2
        BAi[j] = (Bim * Are[j] - Bre * Aim[j]) * inv;
    }
    float d1 = Aim[1] - Aim[0], d2 = Aim[2] - Aim[1], d3 = Aim[3] - Aim[2];
    return (Are[1] == Are[0]) && (Are[2] == Are[0]) && (Are[3] == Are[0]) &&
           (d1 == d2) && (d2 == d3);
}

// ---------------------------------------------------------------------------
// Kernel 1: dt = softplus(u@xprojT@dtwT + b); writes du[l][h] = (dt, u/dt).
// dt_w read directly as per-lane contiguous float4 (no transpose pass).
// ---------------------------------------------------------------------------
__global__ __launch_bounds__(256) void k_dt(const float* __restrict__ u,
                                            const float* __restrict__ xproj_w,
                                            const float* __restrict__ dt_w,
                                            const float* __restrict__ dt_b,
                                            float2* __restrict__ du_out) {
    __shared__ float u_s[8][Hd];
    __shared__ float dtu_s[8][Rd];
    const int t = threadIdx.x;
    const int l0 = blockIdx.x * 8;

    #pragma unroll
    for (int i = 0; i < 16; ++i) {
        int idx = t + i * 256;
        ((float*)u_s)[idx] = u[l0 * Hd + idx];
    }
    __syncthreads();

    const int r = t >> 3;
    const int j = t & 7;
    float part[8];
    #pragma unroll
    for (int l = 0; l < 8; ++l) part[l] = 0.f;
    for (int k = 0; k < 64; ++k) {
        float w = xproj_w[r * Hd + k * 8 + j];
        #pragma unroll
        for (int l = 0; l < 8; ++l) part[l] = fmaf(u_s[l][k * 8 + j], w, part[l]);
    }
    #pragma unroll
    for (int off = 1; off < 8; off <<= 1) {
        #pragma unroll
        for (int l = 0; l < 8; ++l) part[l] += __shfl_xor(part[l], off);
    }
    if (j == 0) {
        #pragma unroll
        for (int l = 0; l < 8; ++l) dtu_s[l][r] = part[l];
    }
    __syncthreads();

    #pragma unroll
    for (int hb = 0; hb < 2; ++hb) {
        int h = hb * 256 + t;
        float bias = dt_b[h];
        float acc[8];
        #pragma unroll
        for (int l = 0; l < 8; ++l) acc[l] = bias;
        #pragma unroll
        for (int rb = 0; rb < 8; ++rb) {
            float4 w = *(const float4*)&dt_w[h * Rd + rb * 4];
            #pragma unroll
            for (int l = 0; l < 8; ++l) {
                acc[l] = fmaf(dtu_s[l][rb * 4 + 0], w.x, acc[l]);
                acc[l] = fmaf(dtu_s[l][rb * 4 + 1], w.y, acc[l]);
                acc[l] = fmaf(dtu_s[l][rb * 4 + 2], w.z, acc[l]);
                acc[l] = fmaf(dtu_s[l][rb * 4 + 3], w.w, acc[l]);
            }
        }
        #pragma unroll
        for (int l = 0; l < 8; ++l) {
            float x = acc[l];
            float sp = fmaxf(x, 0.f) + log1pf(__expf(-fabsf(x)));  // softplus
            float uv = u_s[l][h];
            float us = uv * __builtin_amdgcn_rcpf(fmaxf(sp, 1e-30f));
            du_out[(l0 + l) * Hd + h] = make_float2(sp, us);
        }
    }
}

// ---------------------------------------------------------------------------
// Kernel 2: per-chunk scan (h0=0) -> PS[c][chain] = (P.re, P.im, S.re, S.im).
// CLEN=32 prefetched in two 16-position register halves. Grid (128, 8).
// ---------------------------------------------------------------------------
__global__ __launch_bounds__(256) void k_chunk(const float2* __restrict__ du,
        const float* __restrict__ A_log, const float* __restrict__ A_im,
        const float* __restrict__ B_param, float4* __restrict__ PS) {
    const int t = threadIdx.x;
    const int q = t & 3;
    const int hh = blockIdx.y * 64 + (t >> 2);
    const int c = blockIdx.x;
    const int hnb = hh * N2d + q * 4;
    const int lbase = c * CLEN;

    float2 d0[16], d1[16];
    #pragma unroll
    for (int k = 0; k < 16; ++k) d0[k] = du[(lbase + k) * Hd + hh];
    #pragma unroll
    for (int k = 0; k < 16; ++k) d1[k] = du[(lbase + 16 + k) * Hd + hh];

    float Are[4], Aim[4], BAr[4], BAi[4];
    const bool fast = load_consts4(A_log, A_im, B_param, hnb, Are, Aim, BAr, BAi);
    float sr[4] = {0.f, 0.f, 0.f, 0.f}, si[4] = {0.f, 0.f, 0.f, 0.f};
    float sdt = 0.f;
    if (fast) {
        const float Are0 = Are[0], Aim0 = Aim[0], dA = Aim[1] - Aim[0];
        #pragma unroll
        for (int half = 0; half < 2; ++half) {
            #pragma unroll
            for (int k = 0; k < 16; ++k) {
                float2 d = half ? d1[k] : d0[k];
                float dtv = d.x, us = d.y;
                sdt += dtv;
                float er = __expf(dtv * Are0);
                float s0, c0, sd, cd;
                __sincosf(dtv * Aim0, &s0, &c0);
                __sincosf(dtv * dA, &sd, &cd);
                float ar = er * c0, ai = er * s0;
                #pragma unroll
                for (int jj = 0; jj < 4; ++jj) {
                    float gr = fmaf(ar, us, -us);
                    float gi = ai * us;
                    float nr = fmaf(ar, sr[jj], fmaf(-ai, si[jj], fmaf(gr, BAr[jj], -gi * BAi[jj])));
                    float ni = fmaf(ar, si[jj], fmaf( ai, sr[jj], fmaf(gr, BAi[jj],  gi * BAr[jj])));
                    sr[jj] = nr; si[jj] = ni;
                    if (jj < 3) {
                        float tr = fmaf(ar, cd, -ai * sd);
                        ai = fmaf(ai, cd, ar * sd);
                        ar = tr;
                    }
                }
            }
        }
    } else {
        #pragma unroll
        for (int half = 0; half < 2; ++half) {
            #pragma unroll
            for (int k = 0; k < 16; ++k) {
                float2 d = half ? d1[k] : d0[k];
                float dtv = d.x, us = d.y;
                sdt += dtv;
                #pragma unroll
                for (int jj = 0; jj < 4; ++jj) {
                    float er = __expf(dtv * Are[jj]);
                    float s, cc;
                    __sincosf(dtv * Aim[jj], &s, &cc);
                    float ar = er * cc, ai = er * s;
                    float gr = fmaf(ar, us, -us);
                    float gi = ai * us;
                    float nr = fmaf(ar, sr[jj], fmaf(-ai, si[jj], fmaf(gr, BAr[jj], -gi * BAi[jj])));
                    float ni = fmaf(ar, si[jj], fmaf( ai, sr[jj], fmaf(gr, BAi[jj],  gi * BAr[jj])));
                    sr[jj] = nr; si[jj] = ni;
                }
            }
        }
    }
    int base = c * NCH + hnb;
    #pragma unroll
    for (int jj = 0; jj < 4; ++jj) {
        float er = __expf(sdt * Are[jj]);
        float s, cc;
        __sincosf(sdt * Aim[jj], &s, &cc);
        PS[base + jj] = make_float4(er * cc, er * s, sr[jj], si[jj]);
    }
}

// ---------------------------------------------------------------------------
// Kernel 3a: per-(chain, group) combine over NGRP=16 chunks.
// Writes EXCLUSIVE in-group prefix IP[c] = (Pcum, Ilocal) per chunk, and the
// group aggregate Gps. 65536 threads; uniform work, streamed (no lookback —
// round 4 showed lookback re-fetches ~60 MB from HBM + straggler tail).
// ---------------------------------------------------------------------------
__global__ __launch_bounds__(256) void k_group(const float4* __restrict__ PS,
                                               float4* __restrict__ IP,
                                               float4* __restrict__ Gps) {
    int idx = blockIdx.x * 256 + threadIdx.x;   // 0..65535
    int chain = idx & (NCH - 1);
    int g = idx >> 13;                          // 0..7
    float pr = 1.f, pi = 0.f, hr = 0.f, hi = 0.f;
    #pragma unroll
    for (int half = 0; half < 2; ++half) {
        float4 ps[8];
        #pragma unroll
        for (int i = 0; i < 8; ++i)
            ps[i] = PS[(g * NGRP + half * 8 + i) * NCH + chain];
        #pragma unroll
        for (int i = 0; i < 8; ++i) {
            int c = g * NGRP + half * 8 + i;
            IP[c * NCH + chain] = make_float4(pr, pi, hr, hi);
            float nhr = fmaf(ps[i].x, hr, fmaf(-ps[i].y, hi, ps[i].z));
            float nhi = fmaf(ps[i].x, hi, fmaf( ps[i].y, hr, ps[i].w));
            float npr = fmaf(ps[i].x, pr, -ps[i].y * pi);
            float npi = fmaf(ps[i].x, pi,  ps[i].y * pr);
            hr = nhr; hi = nhi; pr = npr; pi = npi;
        }
    }
    Gps[g * NCH + chain] = make_float4(pr, pi, hr, hi);
}

// ---------------------------------------------------------------------------
// Kernel 3b: exclusive scan of the 8 group aggregates per chain -> H0g.
// ---------------------------------------------------------------------------
__global__ __launch_bounds__(256) void k_gscan(const float4* __restrict__ Gps,
                                               float2* __restrict__ H0g) {
    int chain = blockIdx.x * 256 + threadIdx.x;  // 0..8191
    float4 gp[NGROUPS];
    #pragma unroll
    for (int i = 0; i < NGROUPS; ++i)
        gp[i] = Gps[i * NCH + chain];
    float hr = 0.f, hi = 0.f;
    #pragma unroll
    for (int i = 0; i < NGROUPS; ++i) {
        H0g[i * NCH + chain] = make_float2(hr, hi);
        float nr = fmaf(gp[i].x, hr, fmaf(-gp[i].y, hi, gp[i].z));
        float ni = fmaf(gp[i].x, hi, fmaf( gp[i].y, hr, gp[i].w));
        hr = nr; hi = ni;
    }
}

// ---------------------------------------------------------------------------
// Kernel 4: re-scan chunks with correct init; emit y.
// h0 = Ilocal + Pcum * H0g[group]  (all streamed, uniform work).
// ---------------------------------------------------------------------------
__global__ __launch_bounds__(256) void k_scan(const float2* __restrict__ du,
        const float* __restrict__ A_log, const float* __restrict__ A_im,
        const float* __restrict__ B_param, const float* __restrict__ C_param,
        const float* __restrict__ Dp, const float4* __restrict__ IP,
        const float2* __restrict__ H0g, float* __restrict__ out) {
    const int t = threadIdx.x;
    const int q = t & 3;
    const int hh = blockIdx.y * 64 + (t >> 2);
    const int c = blockIdx.x;
    const int g = c / NGRP;
    const int hnb = hh * N2d + q * 4;
    const int lbase = c * CLEN;

    float2 d0[16], d1[16];
    #pragma unroll
    for (int k = 0; k < 16; ++k) d0[k] = du[(lbase + k) * Hd + hh];
    #pragma unroll
    for (int k = 0; k < 16; ++k) d1[k] = du[(lbase + 16 + k) * Hd + hh];

    float Are[4], Aim[4], BAr[4], BAi[4], Cre[4], Cim[4];
    const bool fast = load_consts4(A_log, A_im, B_param, hnb, Are, Aim, BAr, BAi);
    #pragma unroll
    for (int jj = 0; jj < 4; ++jj) {
        Cre[jj] = C_param[2 * (hnb + jj)];
        Cim[jj] = C_param[2 * (hnb + jj) + 1];
    }
    const float Dv = Dp[hh];

    float hr[4], hi[4];
    #pragma unroll
    for (int jj = 0; jj < 4; ++jj) {
        float4 ip = IP[c * NCH + hnb + jj];          // (Pcum, Ilocal)
        float2 hg = H0g[g * NCH + hnb + jj];
        hr[jj] = fmaf(ip.x, hg.x, fmaf(-ip.y, hg.y, ip.z));
        hi[jj] = fmaf(ip.x, hg.y, fmaf( ip.y, hg.x, ip.w));
    }

    if (fast) {
        const float Are0 = Are[0], Aim0 = Aim[0], dA = Aim[1] - Aim[0];
        #pragma unroll
        for (int half = 0; half < 2; ++half) {
            #pragma unroll
            for (int k = 0; k < 16; ++k) {
                int l = lbase + half * 16 + k;
                float2 d = half ? d1[k] : d0[k];
                float dtv = d.x, us = d.y;
                float er = __expf(dtv * Are0);
                float s0, c0, sd, cd;
                __sincosf(dtv * Aim0, &s0, &c0);
                __sincosf(dtv * dA, &sd, &cd);
                float ar = er * c0, ai = er * s0;
                float yv = 0.f;
                #pragma unroll
                for (int jj = 0; jj < 4; ++jj) {
                    float gr = fmaf(ar, us, -us);
                    float gi = ai * us;
                    float nr = fmaf(ar, hr[jj], fmaf(-ai, hi[jj], fmaf(gr, BAr[jj], -gi * BAi[jj])));
                    float ni = fmaf(ar, hi[jj], fmaf( ai, hr[jj], fmaf(gr, BAi[jj],  gi * BAr[jj])));
                    hr[jj] = nr; hi[jj] = ni;
                    yv = fmaf(nr, Cre[jj], fmaf(-ni, Cim[jj], yv));
                    if (jj < 3) {
                        float tr = fmaf(ar, cd, -ai * sd);
                        ai = fmaf(ai, cd, ar * sd);
                        ar = tr;
                    }
                }
                yv += __shfl_xor(yv, 1);
                yv += __shfl_xor(yv, 2);
                if (q == 0) out[l * Hd + hh] = fmaf(dtv * us, Dv, yv);
            }
        }
    } else {
        #pragma unroll
        for (int half = 0; half < 2; ++half) {
            #pragma unroll
            for (int k = 0; k < 16; ++k) {
                int l = lbase + half * 16 + k;
                float2 d = half ? d1[k] : d0[k];
                float dtv = d.x, us = d.y;
                float yv = 0.f;
                #pragma unroll
                for (int jj = 0; jj < 4; ++jj) {
                    float er = __expf(dtv * Are[jj]);
                    float s, cc;
                    __sincosf(dtv * Aim[jj], &s, &cc);
                    float ar = er * cc, ai = er * s;
                    float gr = fmaf(ar, us, -us);
                    float gi = ai * us;
                    float nr = fmaf(ar, hr[jj], fmaf(-ai, hi[jj], fmaf(gr, BAr[jj], -gi * BAi[jj])));
                    float ni = fmaf(ar, hi[jj], fmaf( ai, hr[jj], fmaf(gr, BAi[jj],  gi * BAr[jj])));
                    hr[jj] = nr; hi[jj] = ni;
                    yv = fmaf(nr, Cre[jj], fmaf(-ni, Cim[jj], yv));
                }
                yv += __shfl_xor(yv, 1);
                yv += __shfl_xor(yv, 2);
                if (q == 0) out[l * Hd + hh] = fmaf(dtv * us, Dv, yv);
            }
        }
    }
}

extern "C" void kernel_launch(void* const* d_in, const int* in_sizes, int n_in,
                              void* d_out, int out_size, void* d_ws, size_t ws_size,
                              hipStream_t stream) {
    const float* u        = (const float*)d_in[0];
    const float* A_log    = (const float*)d_in[1];
    const float* A_im     = (const float*)d_in[2];
    const float* B_param  = (const float*)d_in[3];
    const float* C_param  = (const float*)d_in[4];
    const float* Dp       = (const float*)d_in[5];
    const float* dt_w     = (const float*)d_in[6];
    const float* dt_b     = (const float*)d_in[7];
    const float* xproj_w  = (const float*)d_in[8];

    // ws layout: du[L*H f2] | PS[NCHUNK*NCH f4] | IP[NCHUNK*NCH f4]
    //          | Gps[NGROUPS*NCH f4] | H0g[NGROUPS*NCH f2]
    float2* du  = (float2*)d_ws;
    float4* PS  = (float4*)(du + (size_t)Ld * Hd);
    float4* IP  = PS + (size_t)NCHUNK * NCH;
    float4* Gps = IP + (size_t)NCHUNK * NCH;
    float2* H0g = (float2*)(Gps + (size_t)NGROUPS * NCH);
    float*  out = (float*)d_out;

    k_dt<<<Ld / 8, 256, 0, stream>>>(u, xproj_w, dt_w, dt_b, du);
    dim3 g2(NCHUNK, Hd / 64);
    k_chunk<<<g2, 256, 0, stream>>>(du, A_log, A_im, B_param, PS);
    k_group<<<(NCH * NGROUPS) / 256, 256, 0, stream>>>(PS, IP, Gps);
    k_gscan<<<NCH / 256, 256, 0, stream>>>(Gps, H0g);
    k_scan<<<g2, 256, 0, stream>>>(du, A_log, A_im, B_param, C_param, Dp,
                                   IP, H0g, out);
}